// Round 5
// baseline (872.388 us; speedup 1.0000x reference)
//
#include <hip/hip_runtime.h>
#include <hip/hip_cooperative_groups.h>

namespace cg = cooperative_groups;

// Transformer_F: Z <- Z + (1/H) sum_h (Z Q_h Z^T)(Z V_h^T)/N, 4 layers.
// Reassociated: G_b = Z_b^T Z_b ; W_b = (1/(N*H)) sum_h Q_h G_b V_h^T ; Z_b += Z_b W_b.
// Single cooperative kernel; WG (s,b) keeps Z rows [s*64,(s+1)*64) of batch b
// resident in LDS across all layers. Per layer:
//   [phase A/D wrote Gpart] -> grid.sync -> B: reduce Gpart->G
//   -> grid.sync -> C: W_b rows [4s,4s+4) = scale*sum_h Q_h G_b V_h^T  (G chunked, U in regs)
//   -> grid.sync -> D: zs += zs@W_b (+ next Gram partial, or Zout store on last layer)
// Static LDS: zs 33.8KB + cbuf 16.9KB = 50.7KB (< 64KB static limit; 1 WG/CU).

constexpr int B  = 8;
constexpr int N  = 2048;
constexpr int D  = 128;
constexpr int NL = 4;
constexpr int NH = 8;
constexpr int SP = 32;          // N-splits (grid = SP*B = 256 WGs, 1 per CU)
constexpr int RPS = N / SP;     // 64 rows per WG
constexpr int PAD = 132;        // padded LDS row stride (floats, 16B-aligned)

__global__ __launch_bounds__(256, 1) void k_mega(
    const float* __restrict__ Zin,
    const float* __restrict__ Vm,     // [NL][NH][D][D]
    const float* __restrict__ Qm,     // [NL][NH][D][D]
    float* __restrict__ Zout,         // [B][N][D]
    float* __restrict__ Gpart,        // ws: [B][SP][D][D]
    float* __restrict__ G,            // ws: [B][D][D]
    float* __restrict__ W) {          // ws: [B][D][D]
  cg::grid_group grid = cg::this_grid();
  const int s = blockIdx.x, b = blockIdx.y;
  const int t = threadIdx.x;
  const int wlin = b * SP + s;        // 0..255

  __shared__ float zs[RPS][PAD];      // resident Z tile (33.8 KB)
  __shared__ float cbuf[32][PAD];     // phase C: G chunk, then all-head U rows (16.9 KB)

  // ---- phase A (once): load Z tile; initial Gram partial
  {
    const float* Zb = Zin + ((size_t)b * N + (size_t)s * RPS) * D;
#pragma unroll
    for (int j = 0; j < 8; ++j) {
      int fi = t + j * 256;           // float4 index into 64x128
      int row = fi >> 5, c4 = fi & 31;
      *(float4*)&zs[row][c4 * 4] = ((const float4*)Zb)[fi];
    }
    __syncthreads();
    const int ti = t >> 4, tj = t & 15;
    float g[8][8];
#pragma unroll
    for (int i = 0; i < 8; ++i)
#pragma unroll
      for (int j = 0; j < 8; ++j) g[i][j] = 0.0f;
#pragma unroll 4
    for (int k = 0; k < RPS; ++k) {
      float a[8], bb[8];
      *(float4*)&a[0]  = *(const float4*)&zs[k][ti * 8];
      *(float4*)&a[4]  = *(const float4*)&zs[k][ti * 8 + 4];
      *(float4*)&bb[0] = *(const float4*)&zs[k][tj * 8];
      *(float4*)&bb[4] = *(const float4*)&zs[k][tj * 8 + 4];
#pragma unroll
      for (int i = 0; i < 8; ++i)
#pragma unroll
        for (int j = 0; j < 8; ++j)
          g[i][j] = fmaf(a[i], bb[j], g[i][j]);
    }
    float* out = Gpart + ((size_t)b * SP + s) * D * D;
#pragma unroll
    for (int i = 0; i < 8; ++i)
#pragma unroll
      for (int j = 0; j < 2; ++j)
        *(float4*)&out[(ti * 8 + i) * D + tj * 8 + j * 4] =
            make_float4(g[i][j*4], g[i][j*4+1], g[i][j*4+2], g[i][j*4+3]);
  }

  for (int l = 0; l < NL; ++l) {
    grid.sync();                      // Gpart ready (phase A or prev phase D)

    // ---- phase B: reduce Gpart -> G. Each WG owns 128 float4 of G.
    if (t < 128) {
      int f4 = wlin * 128 + t;        // global float4 idx in [0, 32768)
      int b2 = f4 >> 12, rest = f4 & 4095;
      const float4* src = (const float4*)Gpart;
      float4 a = make_float4(0.f, 0.f, 0.f, 0.f);
#pragma unroll 8
      for (int sp = 0; sp < SP; ++sp) {
        float4 v = src[(size_t)(b2 * SP + sp) * (D * D / 4) + rest];
        a.x += v.x; a.y += v.y; a.z += v.z; a.w += v.w;
      }
      ((float4*)G)[f4] = a;
    }
    grid.sync();                      // G ready

    // ---- phase C: W_b rows [4s, 4s+4) = scale * sum_h Q_h[rows,:] G_b V_h^T
    // G processed in 4 chunks of 32 rows through cbuf; U accumulated in registers
    // (us_reg[h][2], statically indexed); Q read direct (wave-uniform -> broadcast).
    {
      const float* Gb = G + (size_t)b * D * D;
      const float* Ql = Qm + (size_t)l * NH * D * D;
      const float* Vl = Vm + (size_t)l * NH * D * D;
      const int p0 = s * 4;
      const int p  = t >> 6;          // 0..3 (row within chunk; constant per wave)
      const int c2 = t & 63;          // QG: 2 columns per thread
      float us_reg[NH][2];
#pragma unroll
      for (int h = 0; h < NH; ++h) { us_reg[h][0] = 0.f; us_reg[h][1] = 0.f; }

      for (int qc = 0; qc < 4; ++qc) {
        __syncthreads();              // prev chunk's cbuf reads done
#pragma unroll
        for (int j = 0; j < 4; ++j) { // stage G rows [32qc, 32qc+32): 1024 float4
          int fi = t + j * 256;
          int row = fi >> 5, c4 = fi & 31;
          *(float4*)&cbuf[row][c4 * 4] =
              ((const float4*)(Gb + (size_t)qc * 32 * D))[fi];
        }
        __syncthreads();              // chunk ready
#pragma unroll
        for (int h = 0; h < NH; ++h) {
          const float* Qrow = Ql + ((size_t)h * D + (p0 + p)) * D + qc * 32;
          float u0 = us_reg[h][0], u1 = us_reg[h][1];
#pragma unroll
          for (int q4 = 0; q4 < 8; ++q4) {
            float4 qv = *(const float4*)&Qrow[q4 * 4];   // wave-uniform broadcast
            float2 g0 = *(const float2*)&cbuf[q4 * 4 + 0][c2 * 2];
            float2 g1 = *(const float2*)&cbuf[q4 * 4 + 1][c2 * 2];
            float2 g2 = *(const float2*)&cbuf[q4 * 4 + 2][c2 * 2];
            float2 g3 = *(const float2*)&cbuf[q4 * 4 + 3][c2 * 2];
            u0 = fmaf(qv.x, g0.x, u0); u1 = fmaf(qv.x, g0.y, u1);
            u0 = fmaf(qv.y, g1.x, u0); u1 = fmaf(qv.y, g1.y, u1);
            u0 = fmaf(qv.z, g2.x, u0); u1 = fmaf(qv.z, g2.y, u1);
            u0 = fmaf(qv.w, g3.x, u0); u1 = fmaf(qv.w, g3.y, u1);
          }
          us_reg[h][0] = u0; us_reg[h][1] = u1;
        }
      }
      __syncthreads();                // last chunk's reads done; reuse cbuf for U
#pragma unroll
      for (int h = 0; h < NH; ++h) {  // cbuf[h*4+p][c] = U_h[p][c]
        cbuf[h * 4 + p][c2 * 2]     = us_reg[h][0];
        cbuf[h * 4 + p][c2 * 2 + 1] = us_reg[h][1];
      }
      __syncthreads();                // all U rows visible
      const int i = t & 63;           // WV: output col (and i+64)
      float wa = 0.f, wb = 0.f;
#pragma unroll
      for (int h = 0; h < NH; ++h) {
        const float* Vh = Vl + (size_t)h * D * D;
#pragma unroll 4
        for (int c4 = 0; c4 < 32; ++c4) {
          float4 u  = *(const float4*)&cbuf[h * 4 + p][c4 * 4];   // LDS broadcast
          float4 va = *(const float4*)&Vh[(size_t)i * D + c4 * 4];
          float4 vb = *(const float4*)&Vh[(size_t)(i + 64) * D + c4 * 4];
          wa = fmaf(u.x, va.x, wa); wb = fmaf(u.x, vb.x, wb);
          wa = fmaf(u.y, va.y, wa); wb = fmaf(u.y, vb.y, wb);
          wa = fmaf(u.z, va.z, wa); wb = fmaf(u.z, vb.z, wb);
          wa = fmaf(u.w, va.w, wa); wb = fmaf(u.w, vb.w, wb);
        }
      }
      const float scale = 1.0f / ((float)N * (float)NH);
      float* Wb = W + (size_t)b * D * D;
      Wb[(size_t)(p0 + p) * D + i]      = wa * scale;
      Wb[(size_t)(p0 + p) * D + i + 64] = wb * scale;
    }
    grid.sync();                      // W ready

    // ---- phase D: zs += zs @ W_b ; Gram partial of new zs (or Zout store last layer)
    {
      const float* Wb = W + (size_t)b * D * D;
      const int ni = t >> 5, ii = t & 31;
      const int n0 = ni * 8;
      float acc[8][4];
#pragma unroll
      for (int i = 0; i < 8; ++i) {   // residual init: out = Z + Z@W
        float4 z0 = *(const float4*)&zs[n0 + i][ii * 4];
        acc[i][0] = z0.x; acc[i][1] = z0.y; acc[i][2] = z0.z; acc[i][3] = z0.w;
      }
#pragma unroll 2
      for (int p4 = 0; p4 < 32; ++p4) {
        float wreg[4][4];
#pragma unroll
        for (int k = 0; k < 4; ++k)   // coalesced, L2-hot
          *(float4*)wreg[k] = *(const float4*)&Wb[(size_t)(p4 * 4 + k) * D + ii * 4];
#pragma unroll
        for (int i = 0; i < 8; ++i) {
          float zreg[4];
          *(float4*)zreg = *(const float4*)&zs[n0 + i][p4 * 4];
#pragma unroll
          for (int k = 0; k < 4; ++k)
#pragma unroll
            for (int c = 0; c < 4; ++c)
              acc[i][c] = fmaf(zreg[k], wreg[k][c], acc[i][c]);
        }
      }
      __syncthreads();                 // all reads of old zs complete
      float* Zb = Zout + ((size_t)b * N + (size_t)s * RPS) * D;
#pragma unroll
      for (int i = 0; i < 8; ++i) {
        float4 v = make_float4(acc[i][0], acc[i][1], acc[i][2], acc[i][3]);
        *(float4*)&zs[n0 + i][ii * 4] = v;
        if (l == NL - 1)
          *(float4*)&Zb[(size_t)(n0 + i) * D + ii * 4] = v;
      }
      if (l < NL - 1) {
        __syncthreads();               // new zs visible to all
        const int ti = t >> 4, tj = t & 15;
        float g[8][8];
#pragma unroll
        for (int i = 0; i < 8; ++i)
#pragma unroll
          for (int j = 0; j < 8; ++j) g[i][j] = 0.0f;
#pragma unroll 4
        for (int k = 0; k < RPS; ++k) {
          float a[8], bb[8];
          *(float4*)&a[0]  = *(const float4*)&zs[k][ti * 8];
          *(float4*)&a[4]  = *(const float4*)&zs[k][ti * 8 + 4];
          *(float4*)&bb[0] = *(const float4*)&zs[k][tj * 8];
          *(float4*)&bb[4] = *(const float4*)&zs[k][tj * 8 + 4];
#pragma unroll
          for (int i = 0; i < 8; ++i)
#pragma unroll
            for (int j = 0; j < 8; ++j)
              g[i][j] = fmaf(a[i], bb[j], g[i][j]);
        }
        float* out = Gpart + ((size_t)b * SP + s) * D * D;
#pragma unroll
        for (int i = 0; i < 8; ++i)
#pragma unroll
          for (int j = 0; j < 2; ++j)
            *(float4*)&out[(ti * 8 + i) * D + tj * 8 + j * 4] =
                make_float4(g[i][j*4], g[i][j*4+1], g[i][j*4+2], g[i][j*4+3]);
      }
    }
  }
}

extern "C" void kernel_launch(void* const* d_in, const int* in_sizes, int n_in,
                              void* d_out, int out_size, void* d_ws, size_t ws_size,
                              hipStream_t stream) {
  const float* Zin = (const float*)d_in[0];
  const float* Vm  = (const float*)d_in[1];   // [NL][NH][1][D][D]
  const float* Qm  = (const float*)d_in[2];   // [NL][NH][1][D][D]
  float* Zout = (float*)d_out;

  // workspace layout (17 MB):
  //   [0, 16MB)        : Gpart [B][SP][D][D]
  //   [16MB, +512KB)   : G     [B][D][D]
  //   [16.5MB, +512KB) : W     [B][D][D]
  char* ws = (char*)d_ws;
  float* Gpart = (float*)ws;
  float* G     = (float*)(ws + (size_t)B * SP * D * D * sizeof(float));
  float* W     = (float*)(ws + (size_t)B * SP * D * D * sizeof(float)
                             + (size_t)B * D * D * sizeof(float));

  void* kargs[] = {(void*)&Zin, (void*)&Vm, (void*)&Qm, (void*)&Zout,
                   (void*)&Gpart, (void*)&G, (void*)&W};
  hipLaunchCooperativeKernel((const void*)k_mega, dim3(SP, B, 1), dim3(256, 1, 1),
                             kargs, 0u, stream);
}

// Round 6
// 759.495 us; speedup vs baseline: 1.1486x; 1.1486x over previous
//
#include <hip/hip_runtime.h>
#include <hip/hip_cooperative_groups.h>

namespace cg = cooperative_groups;

// Transformer_F: Z <- Z + (1/H) sum_h (Z Q_h Z^T)(Z V_h^T)/N, 4 layers.
// Reassociated: G_b = Z_b^T Z_b ; W_b = (1/(N*H)) sum_h Q_h G_b V_h^T ; Z_b += Z_b W_b.
// Single cooperative kernel, grid = SP*B = 256 WGs (1/CU). WG (s,b) keeps Z rows
// [s*64,(s+1)*64) of batch b resident in LDS across all layers.
//   phase T (once): V -> Vt (transposed, [l][h][c][i]) so WV reads are coalesced
//   phase A (once): load Z tile, initial Gram partial -> Gpart
//   per layer: grid.sync -> B: reduce Gpart->G -> grid.sync
//              -> C: W rows [4s,4s+4): QG direct-global (coalesced) -> U in cbuf
//                    -> WV via Vt (coalesced)          -> grid.sync
//              -> D: zs += zs@W (+ next Gram partial | Zout store on last layer)
// Round-5 lesson: stride-512 per-lane V gathers (64 lines/instr) dominated (~500us).
// All phase-C accesses are now lane-contiguous.

constexpr int B  = 8;
constexpr int N  = 2048;
constexpr int D  = 128;
constexpr int NL = 4;
constexpr int NH = 8;
constexpr int SP = 32;          // N-splits (grid = SP*B = 256 WGs)
constexpr int RPS = N / SP;     // 64 rows per WG
constexpr int PAD = 132;        // padded LDS row stride for zs (floats)

__global__ __launch_bounds__(256, 1) void k_mega(
    const float* __restrict__ Zin,
    const float* __restrict__ Vm,     // [NL][NH][D][D]
    const float* __restrict__ Qm,     // [NL][NH][D][D]
    float* Zout,                      // [B][N][D] (first 2MB doubles as Vt scratch)
    float* __restrict__ Gpart,        // ws: [B][SP][D][D]
    float* __restrict__ G,            // ws: [B][D][D]
    float* __restrict__ W,            // ws: [B][D][D]
    float* Vt) {                      // = Zout base: [NL][NH][D][D], Vt[l][h][c][i]
  cg::grid_group grid = cg::this_grid();
  const int s = blockIdx.x, b = blockIdx.y;
  const int t = threadIdx.x;
  const int wlin = b * SP + s;        // 0..255

  __shared__ float zs[RPS][PAD];      // resident Z tile (33.8 KB)
  __shared__ float cbuf[32][D];       // phase T transpose staging / phase C U rows (16.4 KB)

  // ---- phase T (once): transpose V into Vt. 8 WGs per (l,h) tile, 16 i-rows each.
  {
    const int tile = wlin >> 3;       // 0..31 -> flat (l,h)
    const int i0 = (wlin & 7) * 16;   // i-block of 16 rows
    const float* Vsrc = Vm + (size_t)tile * D * D;
    float* Vdst = Vt + (size_t)tile * D * D;
#pragma unroll
    for (int j = 0; j < 2; ++j) {     // load 16x128 tile (512 float4), coalesced
      int fi = t + j * 256;
      int row = fi >> 5, c4 = fi & 31;
      *(float4*)&cbuf[row][c4 * 4] =
          ((const float4*)(Vsrc + (size_t)(i0 + row) * D))[c4];
    }
    __syncthreads();
#pragma unroll
    for (int j = 0; j < 2; ++j) {     // write 128c x 16i transposed, coalesced in i
      int fi = t + j * 256;
      int c = fi >> 2, i4 = fi & 3;
      float4 v = make_float4(cbuf[i4 * 4 + 0][c], cbuf[i4 * 4 + 1][c],
                             cbuf[i4 * 4 + 2][c], cbuf[i4 * 4 + 3][c]);
      *(float4*)&Vdst[(size_t)c * D + i0 + i4 * 4] = v;
    }
    __syncthreads();
  }

  // ---- phase A (once): load Z tile; initial Gram partial
  {
    const float* Zb = Zin + ((size_t)b * N + (size_t)s * RPS) * D;
#pragma unroll
    for (int j = 0; j < 8; ++j) {
      int fi = t + j * 256;           // float4 index into 64x128
      int row = fi >> 5, c4 = fi & 31;
      *(float4*)&zs[row][c4 * 4] = ((const float4*)Zb)[fi];
    }
    __syncthreads();
    const int ti = t >> 4, tj = t & 15;
    float g[8][8];
#pragma unroll
    for (int i = 0; i < 8; ++i)
#pragma unroll
      for (int j = 0; j < 8; ++j) g[i][j] = 0.0f;
#pragma unroll 4
    for (int k = 0; k < RPS; ++k) {
      float a[8], bb[8];
      *(float4*)&a[0]  = *(const float4*)&zs[k][ti * 8];
      *(float4*)&a[4]  = *(const float4*)&zs[k][ti * 8 + 4];
      *(float4*)&bb[0] = *(const float4*)&zs[k][tj * 8];
      *(float4*)&bb[4] = *(const float4*)&zs[k][tj * 8 + 4];
#pragma unroll
      for (int i = 0; i < 8; ++i)
#pragma unroll
        for (int j = 0; j < 8; ++j)
          g[i][j] = fmaf(a[i], bb[j], g[i][j]);
    }
    float* out = Gpart + ((size_t)b * SP + s) * D * D;
#pragma unroll
    for (int i = 0; i < 8; ++i)
#pragma unroll
      for (int j = 0; j < 2; ++j)
        *(float4*)&out[(ti * 8 + i) * D + tj * 8 + j * 4] =
            make_float4(g[i][j*4], g[i][j*4+1], g[i][j*4+2], g[i][j*4+3]);
  }

  for (int l = 0; l < NL; ++l) {
    grid.sync();                      // Gpart ready (phase A or prev phase D)

    // ---- phase B: reduce Gpart -> G. Each WG owns 128 float4 of G.
    if (t < 128) {
      int f4 = wlin * 128 + t;        // global float4 idx in [0, 32768)
      int b2 = f4 >> 12, rest = f4 & 4095;
      const float4* src = (const float4*)Gpart;
      float4 a = make_float4(0.f, 0.f, 0.f, 0.f);
#pragma unroll 8
      for (int sp = 0; sp < SP; ++sp) {
        float4 v = src[(size_t)(b2 * SP + sp) * (D * D / 4) + rest];
        a.x += v.x; a.y += v.y; a.z += v.z; a.w += v.w;
      }
      ((float4*)G)[f4] = a;
    }
    grid.sync();                      // G ready

    // ---- phase C: W_b rows [4s, 4s+4) = scale * sum_h Q_h[rows,:] G_b V_h^T
    {
      const float* Gb  = G  + (size_t)b * D * D;
      const float* Ql  = Qm + (size_t)l * NH * D * D;
      const float* Vtl = Vt + (size_t)l * NH * D * D;
      const int p0 = s * 4;
      const int p  = t >> 6;          // 0..3 (wave-uniform)
      const int c2 = t & 63;          // lane: owns cols (2c2, 2c2+1)
      float us_reg[NH][2];
#pragma unroll
      for (int h = 0; h < NH; ++h) { us_reg[h][0] = 0.f; us_reg[h][1] = 0.f; }
      // QG: U_h[p][2c2..] = sum_q Q_h[p0+p][q] * G[q][2c2..]; all reads coalesced/uniform
      for (int q4 = 0; q4 < 32; ++q4) {
        float4 qv[NH];
#pragma unroll
        for (int h = 0; h < NH; ++h)  // wave-uniform float4 (broadcast line)
          qv[h] = *(const float4*)&Ql[((size_t)h * D + (p0 + p)) * D + q4 * 4];
        float2 g2[4];
#pragma unroll
        for (int r = 0; r < 4; ++r)   // lanes sweep contiguous 512B of G row
          g2[r] = *(const float2*)&Gb[(size_t)(q4 * 4 + r) * D + 2 * c2];
#pragma unroll
        for (int h = 0; h < NH; ++h) {
          us_reg[h][0] = fmaf(qv[h].x, g2[0].x, us_reg[h][0]);
          us_reg[h][1] = fmaf(qv[h].x, g2[0].y, us_reg[h][1]);
          us_reg[h][0] = fmaf(qv[h].y, g2[1].x, us_reg[h][0]);
          us_reg[h][1] = fmaf(qv[h].y, g2[1].y, us_reg[h][1]);
          us_reg[h][0] = fmaf(qv[h].z, g2[2].x, us_reg[h][0]);
          us_reg[h][1] = fmaf(qv[h].z, g2[2].y, us_reg[h][1]);
          us_reg[h][0] = fmaf(qv[h].w, g2[3].x, us_reg[h][0]);
          us_reg[h][1] = fmaf(qv[h].w, g2[3].y, us_reg[h][1]);
        }
      }
      __syncthreads();                // safe to overwrite cbuf
#pragma unroll
      for (int h = 0; h < NH; ++h)    // hand U across lanes via LDS
        *(float2*)&cbuf[h * 4 + p][2 * c2] = make_float2(us_reg[h][0], us_reg[h][1]);
      __syncthreads();                // all U rows visible
      // WV: W[p0+p][2iq..] = scale * sum_h sum_c U_h[p][c] * Vt_h[c][2iq..]
      const int iq = t & 63;
      float wa = 0.f, wb = 0.f;
#pragma unroll
      for (int h = 0; h < NH; ++h) {
        const float* Vth  = Vtl + (size_t)h * D * D;
        const float* Urow = cbuf[h * 4 + p];
#pragma unroll 4
        for (int c4 = 0; c4 < 32; ++c4) {
          float4 u = *(const float4*)&Urow[c4 * 4];   // wave-uniform LDS broadcast
          float2 v0 = *(const float2*)&Vth[(size_t)(c4 * 4 + 0) * D + 2 * iq];
          float2 v1 = *(const float2*)&Vth[(size_t)(c4 * 4 + 1) * D + 2 * iq];
          float2 v2 = *(const float2*)&Vth[(size_t)(c4 * 4 + 2) * D + 2 * iq];
          float2 v3 = *(const float2*)&Vth[(size_t)(c4 * 4 + 3) * D + 2 * iq];
          wa = fmaf(u.x, v0.x, wa); wb = fmaf(u.x, v0.y, wb);
          wa = fmaf(u.y, v1.x, wa); wb = fmaf(u.y, v1.y, wb);
          wa = fmaf(u.z, v2.x, wa); wb = fmaf(u.z, v2.y, wb);
          wa = fmaf(u.w, v3.x, wa); wb = fmaf(u.w, v3.y, wb);
        }
      }
      const float scale = 1.0f / ((float)N * (float)NH);
      float* Wb = W + (size_t)b * D * D;
      *(float2*)&Wb[(size_t)(p0 + p) * D + 2 * iq] =
          make_float2(wa * scale, wb * scale);
    }
    grid.sync();                      // W ready

    // ---- phase D: zs += zs @ W_b ; Gram partial of new zs (or Zout store last layer)
    {
      const float* Wb = W + (size_t)b * D * D;
      const int ni = t >> 5, ii = t & 31;
      const int n0 = ni * 8;
      float acc[8][4];
#pragma unroll
      for (int i = 0; i < 8; ++i) {   // residual init: out = Z + Z@W
        float4 z0 = *(const float4*)&zs[n0 + i][ii * 4];
        acc[i][0] = z0.x; acc[i][1] = z0.y; acc[i][2] = z0.z; acc[i][3] = z0.w;
      }
#pragma unroll 2
      for (int p4 = 0; p4 < 32; ++p4) {
        float wreg[4][4];
#pragma unroll
        for (int k = 0; k < 4; ++k)   // coalesced, L2-hot
          *(float4*)wreg[k] = *(const float4*)&Wb[(size_t)(p4 * 4 + k) * D + ii * 4];
#pragma unroll
        for (int i = 0; i < 8; ++i) {
          float zreg[4];
          *(float4*)zreg = *(const float4*)&zs[n0 + i][p4 * 4];
#pragma unroll
          for (int k = 0; k < 4; ++k)
#pragma unroll
            for (int c = 0; c < 4; ++c)
              acc[i][c] = fmaf(zreg[k], wreg[k][c], acc[i][c]);
        }
      }
      __syncthreads();                 // all reads of old zs complete
      float* Zb = Zout + ((size_t)b * N + (size_t)s * RPS) * D;
#pragma unroll
      for (int i = 0; i < 8; ++i) {
        float4 v = make_float4(acc[i][0], acc[i][1], acc[i][2], acc[i][3]);
        *(float4*)&zs[n0 + i][ii * 4] = v;
        if (l == NL - 1)
          *(float4*)&Zb[(size_t)(n0 + i) * D + ii * 4] = v;
      }
      if (l < NL - 1) {
        __syncthreads();               // new zs visible to all
        const int ti = t >> 4, tj = t & 15;
        float g[8][8];
#pragma unroll
        for (int i = 0; i < 8; ++i)
#pragma unroll
          for (int j = 0; j < 8; ++j) g[i][j] = 0.0f;
#pragma unroll 4
        for (int k = 0; k < RPS; ++k) {
          float a[8], bb[8];
          *(float4*)&a[0]  = *(const float4*)&zs[k][ti * 8];
          *(float4*)&a[4]  = *(const float4*)&zs[k][ti * 8 + 4];
          *(float4*)&bb[0] = *(const float4*)&zs[k][tj * 8];
          *(float4*)&bb[4] = *(const float4*)&zs[k][tj * 8 + 4];
#pragma unroll
          for (int i = 0; i < 8; ++i)
#pragma unroll
            for (int j = 0; j < 8; ++j)
              g[i][j] = fmaf(a[i], bb[j], g[i][j]);
        }
        float* out = Gpart + ((size_t)b * SP + s) * D * D;
#pragma unroll
        for (int i = 0; i < 8; ++i)
#pragma unroll
          for (int j = 0; j < 2; ++j)
            *(float4*)&out[(ti * 8 + i) * D + tj * 8 + j * 4] =
                make_float4(g[i][j*4], g[i][j*4+1], g[i][j*4+2], g[i][j*4+3]);
      }
    }
  }
}

extern "C" void kernel_launch(void* const* d_in, const int* in_sizes, int n_in,
                              void* d_out, int out_size, void* d_ws, size_t ws_size,
                              hipStream_t stream) {
  const float* Zin = (const float*)d_in[0];
  const float* Vm  = (const float*)d_in[1];   // [NL][NH][1][D][D]
  const float* Qm  = (const float*)d_in[2];   // [NL][NH][1][D][D]
  float* Zout = (float*)d_out;
  // Vt (2 MB) lives in the first quarter of d_out: d_out is only written as Zout
  // in the LAST layer's phase D, which is strictly after the last Vt read
  // (layer-3 phase C) — separated by a grid.sync. Saves workspace growth.
  float* Vt = Zout;

  // workspace layout (17 MB):
  //   [0, 16MB)        : Gpart [B][SP][D][D]
  //   [16MB, +512KB)   : G     [B][D][D]
  //   [16.5MB, +512KB) : W     [B][D][D]
  char* ws = (char*)d_ws;
  float* Gpart = (float*)ws;
  float* G     = (float*)(ws + (size_t)B * SP * D * D * sizeof(float));
  float* W     = (float*)(ws + (size_t)B * SP * D * D * sizeof(float)
                             + (size_t)B * D * D * sizeof(float));

  void* kargs[] = {(void*)&Zin, (void*)&Vm, (void*)&Qm, (void*)&Zout,
                   (void*)&Gpart, (void*)&G, (void*)&W, (void*)&Vt};
  hipLaunchCooperativeKernel((const void*)k_mega, dim3(SP, B, 1), dim3(256, 1, 1),
                             kargs, 0u, stream);
}

// Round 7
// 741.941 us; speedup vs baseline: 1.1758x; 1.0237x over previous
//
#include <hip/hip_runtime.h>
#include <hip/hip_cooperative_groups.h>

namespace cg = cooperative_groups;

// Transformer_F: Z <- Z + (1/H) sum_h (Z Q_h Z^T)(Z V_h^T)/N, 4 layers.
// Reassociated: G_b = Z_b^T Z_b ; W_b = (1/(N*H)) sum_h Q_h G_b V_h^T ; Z_b += Z_b W_b.
// Cooperative kernel, grid = 256 WGs (1/CU) x 1024 threads (16 waves/CU = 4/SIMD).
// Round-6 lesson: 256-thread WGs gave 1 wave/SIMD -> pure latency-bound (VALUBusy 7.8%).
// This round: same phases, 4x thread parallelism per WG for TLP.

constexpr int B  = 8;
constexpr int N  = 2048;
constexpr int D  = 128;
constexpr int NL = 4;
constexpr int NH = 8;
constexpr int SP = 32;          // N-splits (grid = SP*B = 256 WGs)
constexpr int RPS = N / SP;     // 64 rows per WG
constexpr int PAD = 132;        // padded LDS row stride for zs (floats)

__global__ __launch_bounds__(1024, 1) void k_mega(
    const float* __restrict__ Zin,
    const float* __restrict__ Vm,     // [NL][NH][D][D]
    const float* __restrict__ Qm,     // [NL][NH][D][D]
    float* Zout,                      // [B][N][D] (first 2MB doubles as Vt scratch)
    float* __restrict__ Gpart,        // ws: [B][SP][D][D]
    float* __restrict__ G,            // ws: [B][D][D]
    float* __restrict__ W,            // ws: [B][D][D]
    float* Vt) {                      // = Zout base: [NL][NH][D][D], Vt[l][h][c][i]
  cg::grid_group grid = cg::this_grid();
  const int s = blockIdx.x, b = blockIdx.y;
  const int t = threadIdx.x;
  const int wlin = b * SP + s;        // 0..255

  __shared__ float zs[RPS][PAD];      // resident Z tile (33.8 KB)
  __shared__ float cbuf[32][D];       // transpose staging / B-partials / U rows (16.4 KB)
  __shared__ float wbuf[4][4][D];     // phase C WV partials (8 KB)

  // ---- phase T (once): transpose V into Vt. 8 WGs per (l,h) tile, 16 i-rows each.
  {
    const int tile = wlin >> 3;       // 0..31 -> flat (l,h)
    const int i0 = (wlin & 7) * 16;   // i-block of 16 rows
    const float* Vsrc = Vm + (size_t)tile * D * D;
    float* Vdst = Vt + (size_t)tile * D * D;
    if (t < 512) {                    // load 16x128 tile (512 float4), coalesced
      int row = t >> 5, c4 = t & 31;
      *(float4*)&cbuf[row][c4 * 4] =
          ((const float4*)(Vsrc + (size_t)(i0 + row) * D))[c4];
    }
    __syncthreads();
    if (t < 512) {                    // write 128c x 16i transposed
      int c = t >> 2, i4 = t & 3;
      float4 v = make_float4(cbuf[i4 * 4 + 0][c], cbuf[i4 * 4 + 1][c],
                             cbuf[i4 * 4 + 2][c], cbuf[i4 * 4 + 3][c]);
      *(float4*)&Vdst[(size_t)c * D + i0 + i4 * 4] = v;
    }
    __syncthreads();
  }

  // ---- phase A (once): load Z tile; initial Gram partial
  {
    const float* Zb = Zin + ((size_t)b * N + (size_t)s * RPS) * D;
#pragma unroll
    for (int j = 0; j < 2; ++j) {
      int fi = t + j * 1024;          // float4 index into 64x128
      int row = fi >> 5, c4 = fi & 31;
      *(float4*)&zs[row][c4 * 4] = ((const float4*)Zb)[fi];
    }
    __syncthreads();
    const int ti = t >> 5, tj = t & 31;   // 32x32 grid of 4x4 tiles
    float g[4][4];
#pragma unroll
    for (int i = 0; i < 4; ++i)
#pragma unroll
      for (int j = 0; j < 4; ++j) g[i][j] = 0.0f;
#pragma unroll 4
    for (int k = 0; k < RPS; ++k) {
      float a[4], bb[4];
      *(float4*)&a[0]  = *(const float4*)&zs[k][ti * 4];
      *(float4*)&bb[0] = *(const float4*)&zs[k][tj * 4];
#pragma unroll
      for (int i = 0; i < 4; ++i)
#pragma unroll
        for (int j = 0; j < 4; ++j)
          g[i][j] = fmaf(a[i], bb[j], g[i][j]);
    }
    float* out = Gpart + ((size_t)b * SP + s) * D * D;
#pragma unroll
    for (int i = 0; i < 4; ++i)
      *(float4*)&out[(ti * 4 + i) * D + tj * 4] =
          make_float4(g[i][0], g[i][1], g[i][2], g[i][3]);
  }

  for (int l = 0; l < NL; ++l) {
    grid.sync();                      // Gpart ready (phase A or prev phase D)

    // ---- phase B: reduce Gpart -> G. 8 sp-groups x 128 lanes -> partials -> reduce.
    {
      const int sq = t >> 7;          // 0..7 (4 sp each)
      const int f  = t & 127;
      int f4 = wlin * 128 + f;        // global float4 idx in [0, 32768)
      int b2 = f4 >> 12, rest = f4 & 4095;
      const float4* src = (const float4*)Gpart;
      float4 a = make_float4(0.f, 0.f, 0.f, 0.f);
#pragma unroll
      for (int k = 0; k < 4; ++k) {
        int sp = sq * 4 + k;
        float4 v = src[(size_t)(b2 * SP + sp) * (D * D / 4) + rest];
        a.x += v.x; a.y += v.y; a.z += v.z; a.w += v.w;
      }
      ((float4*)cbuf)[sq * 128 + f] = a;
      __syncthreads();
      if (t < 128) {
        float4 acc = make_float4(0.f, 0.f, 0.f, 0.f);
#pragma unroll
        for (int g2 = 0; g2 < 8; ++g2) {
          float4 v = ((const float4*)cbuf)[g2 * 128 + t];
          acc.x += v.x; acc.y += v.y; acc.z += v.z; acc.w += v.w;
        }
        ((float4*)G)[f4] = acc;       // f4 == wlin*128 + t here
      }
    }
    grid.sync();                      // G ready (also fences cbuf reuse below)

    // ---- phase C: W_b rows [4s, 4s+4) = scale * sum_h Q_h[rows,:] G_b V_h^T
    {
      const float* Gb  = G  + (size_t)b * D * D;
      const float* Ql  = Qm + (size_t)l * NH * D * D;
      const float* Vtl = Vt + (size_t)l * NH * D * D;
      const int p0 = s * 4;
      // --- QG: thread = (head h, row-pair pp, col-pair c2); U -> cbuf
      {
        const int h  = t >> 7;        // 0..7 (wave-uniform)
        const int pp = (t >> 6) & 1;  // 0..1 (wave-uniform)
        const int c2 = t & 63;
        const int pa = pp * 2, pb = pp * 2 + 1;
        const float* Qa = Ql + ((size_t)h * D + (p0 + pa)) * D;
        const float* Qb = Ql + ((size_t)h * D + (p0 + pb)) * D;
        float ua0 = 0.f, ua1 = 0.f, ub0 = 0.f, ub1 = 0.f;
        for (int q4 = 0; q4 < 32; ++q4) {
          float4 qa = *(const float4*)&Qa[q4 * 4];   // wave-uniform broadcast
          float4 qb = *(const float4*)&Qb[q4 * 4];
          float2 g0 = *(const float2*)&Gb[(size_t)(q4 * 4 + 0) * D + 2 * c2];
          float2 g1 = *(const float2*)&Gb[(size_t)(q4 * 4 + 1) * D + 2 * c2];
          float2 g2 = *(const float2*)&Gb[(size_t)(q4 * 4 + 2) * D + 2 * c2];
          float2 g3 = *(const float2*)&Gb[(size_t)(q4 * 4 + 3) * D + 2 * c2];
          ua0 = fmaf(qa.x, g0.x, ua0); ua1 = fmaf(qa.x, g0.y, ua1);
          ub0 = fmaf(qb.x, g0.x, ub0); ub1 = fmaf(qb.x, g0.y, ub1);
          ua0 = fmaf(qa.y, g1.x, ua0); ua1 = fmaf(qa.y, g1.y, ua1);
          ub0 = fmaf(qb.y, g1.x, ub0); ub1 = fmaf(qb.y, g1.y, ub1);
          ua0 = fmaf(qa.z, g2.x, ua0); ua1 = fmaf(qa.z, g2.y, ua1);
          ub0 = fmaf(qb.z, g2.x, ub0); ub1 = fmaf(qb.z, g2.y, ub1);
          ua0 = fmaf(qa.w, g3.x, ua0); ua1 = fmaf(qa.w, g3.y, ua1);
          ub0 = fmaf(qb.w, g3.x, ub0); ub1 = fmaf(qb.w, g3.y, ub1);
        }
        // cbuf free since phase B (grid.sync fenced)
        *(float2*)&cbuf[h * 4 + pa][2 * c2] = make_float2(ua0, ua1);
        *(float2*)&cbuf[h * 4 + pb][2 * c2] = make_float2(ub0, ub1);
      }
      __syncthreads();                // all U rows visible
      // --- WV: thread = (row wp, head-pair hs, col iq); partials -> wbuf -> reduce
      {
        const int wp = t >> 8;        // 0..3 (wave-uniform)
        const int hs = (t >> 6) & 3;  // 0..3 (wave-uniform)
        const int iq = t & 63;
        float wa = 0.f, wb = 0.f;
#pragma unroll
        for (int hh = 0; hh < 2; ++hh) {
          const int h2 = hs * 2 + hh;
          const float* Vth  = Vtl + (size_t)h2 * D * D;
          const float* Urow = cbuf[h2 * 4 + wp];
#pragma unroll 4
          for (int c4 = 0; c4 < 32; ++c4) {
            float4 u = *(const float4*)&Urow[c4 * 4];   // wave-uniform LDS broadcast
            float2 v0 = *(const float2*)&Vth[(size_t)(c4 * 4 + 0) * D + 2 * iq];
            float2 v1 = *(const float2*)&Vth[(size_t)(c4 * 4 + 1) * D + 2 * iq];
            float2 v2 = *(const float2*)&Vth[(size_t)(c4 * 4 + 2) * D + 2 * iq];
            float2 v3 = *(const float2*)&Vth[(size_t)(c4 * 4 + 3) * D + 2 * iq];
            wa = fmaf(u.x, v0.x, wa); wb = fmaf(u.x, v0.y, wb);
            wa = fmaf(u.y, v1.x, wa); wb = fmaf(u.y, v1.y, wb);
            wa = fmaf(u.z, v2.x, wa); wb = fmaf(u.z, v2.y, wb);
            wa = fmaf(u.w, v3.x, wa); wb = fmaf(u.w, v3.y, wb);
          }
        }
        wbuf[wp][hs][2 * iq]     = wa;
        wbuf[wp][hs][2 * iq + 1] = wb;
      }
      __syncthreads();
      if (t < 512) {                  // reduce 4 head-pair partials, write W
        const int wp2 = t >> 7, col = t & 127;
        float w = wbuf[wp2][0][col] + wbuf[wp2][1][col] +
                  wbuf[wp2][2][col] + wbuf[wp2][3][col];
        const float scale = 1.0f / ((float)N * (float)NH);
        W[(size_t)b * D * D + (size_t)(p0 + wp2) * D + col] = w * scale;
      }
    }
    grid.sync();                      // W ready

    // ---- phase D: zs += zs @ W_b ; Gram partial of new zs (or Zout store last layer)
    {
      const float* Wb = W + (size_t)b * D * D;
      const int ni = t >> 5, ii = t & 31;   // 32 row-groups x 32 col-groups
      const int n0 = ni * 2;
      float acc[2][4];
#pragma unroll
      for (int i = 0; i < 2; ++i) {   // residual init: out = Z + Z@W
        float4 z0 = *(const float4*)&zs[n0 + i][ii * 4];
        acc[i][0] = z0.x; acc[i][1] = z0.y; acc[i][2] = z0.z; acc[i][3] = z0.w;
      }
#pragma unroll 2
      for (int p4 = 0; p4 < 32; ++p4) {
        float wreg[4][4];
#pragma unroll
        for (int k = 0; k < 4; ++k)   // coalesced, L2-hot
          *(float4*)wreg[k] = *(const float4*)&Wb[(size_t)(p4 * 4 + k) * D + ii * 4];
#pragma unroll
        for (int i = 0; i < 2; ++i) {
          float zreg[4];
          *(float4*)zreg = *(const float4*)&zs[n0 + i][p4 * 4];
#pragma unroll
          for (int k = 0; k < 4; ++k)
#pragma unroll
            for (int c = 0; c < 4; ++c)
              acc[i][c] = fmaf(zreg[k], wreg[k][c], acc[i][c]);
        }
      }
      __syncthreads();                 // all reads of old zs complete
      float* Zb = Zout + ((size_t)b * N + (size_t)s * RPS) * D;
#pragma unroll
      for (int i = 0; i < 2; ++i) {
        float4 v = make_float4(acc[i][0], acc[i][1], acc[i][2], acc[i][3]);
        *(float4*)&zs[n0 + i][ii * 4] = v;
        if (l == NL - 1)
          *(float4*)&Zb[(size_t)(n0 + i) * D + ii * 4] = v;
      }
      if (l < NL - 1) {
        __syncthreads();               // new zs visible to all
        const int ti = t >> 5, tj = t & 31;
        float g[4][4];
#pragma unroll
        for (int i = 0; i < 4; ++i)
#pragma unroll
          for (int j = 0; j < 4; ++j) g[i][j] = 0.0f;
#pragma unroll 4
        for (int k = 0; k < RPS; ++k) {
          float a[4], bb[4];
          *(float4*)&a[0]  = *(const float4*)&zs[k][ti * 4];
          *(float4*)&bb[0] = *(const float4*)&zs[k][tj * 4];
#pragma unroll
          for (int i = 0; i < 4; ++i)
#pragma unroll
            for (int j = 0; j < 4; ++j)
              g[i][j] = fmaf(a[i], bb[j], g[i][j]);
        }
        float* out = Gpart + ((size_t)b * SP + s) * D * D;
#pragma unroll
        for (int i = 0; i < 4; ++i)
          *(float4*)&out[(ti * 4 + i) * D + tj * 4] =
              make_float4(g[i][0], g[i][1], g[i][2], g[i][3]);
      }
    }
  }
}

extern "C" void kernel_launch(void* const* d_in, const int* in_sizes, int n_in,
                              void* d_out, int out_size, void* d_ws, size_t ws_size,
                              hipStream_t stream) {
  const float* Zin = (const float*)d_in[0];
  const float* Vm  = (const float*)d_in[1];   // [NL][NH][1][D][D]
  const float* Qm  = (const float*)d_in[2];   // [NL][NH][1][D][D]
  float* Zout = (float*)d_out;
  // Vt (2 MB) lives in the first quarter of d_out: d_out is only written as Zout
  // in the LAST layer's phase D, strictly after the last Vt read (layer-3 phase C),
  // separated by a grid.sync.
  float* Vt = Zout;

  // workspace layout (17 MB):
  //   [0, 16MB)        : Gpart [B][SP][D][D]
  //   [16MB, +512KB)   : G     [B][D][D]
  //   [16.5MB, +512KB) : W     [B][D][D]
  char* ws = (char*)d_ws;
  float* Gpart = (float*)ws;
  float* G     = (float*)(ws + (size_t)B * SP * D * D * sizeof(float));
  float* W     = (float*)(ws + (size_t)B * SP * D * D * sizeof(float)
                             + (size_t)B * D * D * sizeof(float));

  void* kargs[] = {(void*)&Zin, (void*)&Vm, (void*)&Qm, (void*)&Zout,
                   (void*)&Gpart, (void*)&G, (void*)&W, (void*)&Vt};
  hipLaunchCooperativeKernel((const void*)k_mega, dim3(SP, B, 1), dim3(1024, 1, 1),
                             kargs, 0u, stream);
}

// Round 8
// 326.324 us; speedup vs baseline: 2.6734x; 2.2736x over previous
//
#include <hip/hip_runtime.h>

// Transformer_F: Z <- Z + (1/H) sum_h (Z Q_h Z^T)(Z V_h^T)/N, 4 layers.
// Reassociated: G_b = Z_b^T Z_b ; W_b = (1/(N*H)) sum_h Q_h G_b V_h^T ; Z_b += Z_b W_b.
// Round-7 lesson: cooperative grid.sync on 8 non-coherent XCDs costs ~45us each
// (12 syncs ~= 650us of idle; VALUBusy stuck at 7.8% regardless of occupancy).
// This round: SAME phase math, 16 standard launches (graph nodes), per-phase profiling.
// WV phase restructured as wave-dot + shfl reduce -> V read coalesced, no Vt transpose.

constexpr int B  = 8;
constexpr int N  = 2048;
constexpr int D  = 128;
constexpr int NL = 4;
constexpr int NH = 8;
constexpr int SP = 32;          // N-splits (grid = SP x B per kernel)
constexpr int RPS = N / SP;     // 64 rows per WG
constexpr int PAD = 132;        // padded LDS row stride for zs (floats)

// ---- kernel 1: Gram partial. Gpart[b,s][q][c] = sum_{n in split} Z[b,n,q] Z[b,n,c]
__global__ __launch_bounds__(1024, 1) void k_gram(const float* __restrict__ Zl,
                                                  float* __restrict__ Gpart) {
  const int s = blockIdx.x, b = blockIdx.y;
  const int t = threadIdx.x;
  __shared__ float zs[RPS][PAD];
  const float* Zb = Zl + ((size_t)b * N + (size_t)s * RPS) * D;
#pragma unroll
  for (int j = 0; j < 2; ++j) {
    int fi = t + j * 1024;          // float4 index into 64x128
    int row = fi >> 5, c4 = fi & 31;
    *(float4*)&zs[row][c4 * 4] = ((const float4*)Zb)[fi];
  }
  __syncthreads();
  const int ti = t >> 5, tj = t & 31;   // 32x32 grid of 4x4 tiles
  float g[4][4];
#pragma unroll
  for (int i = 0; i < 4; ++i)
#pragma unroll
    for (int j = 0; j < 4; ++j) g[i][j] = 0.0f;
#pragma unroll 4
  for (int k = 0; k < RPS; ++k) {
    float a[4], bb[4];
    *(float4*)&a[0]  = *(const float4*)&zs[k][ti * 4];
    *(float4*)&bb[0] = *(const float4*)&zs[k][tj * 4];
#pragma unroll
    for (int i = 0; i < 4; ++i)
#pragma unroll
      for (int j = 0; j < 4; ++j)
        g[i][j] = fmaf(a[i], bb[j], g[i][j]);
  }
  float* out = Gpart + ((size_t)b * SP + s) * D * D;
#pragma unroll
  for (int i = 0; i < 4; ++i)
    *(float4*)&out[(ti * 4 + i) * D + tj * 4] =
        make_float4(g[i][0], g[i][1], g[i][2], g[i][3]);
}

// ---- kernel 2: reduce Gpart -> G. Each WG owns 128 float4 of G.
__global__ __launch_bounds__(1024, 1) void k_gred(const float* __restrict__ Gpart,
                                                  float* __restrict__ G) {
  const int s = blockIdx.x, b = blockIdx.y;
  const int t = threadIdx.x;
  const int wlin = b * SP + s;
  __shared__ float4 cbuf[8][128];
  const int sq = t >> 7;          // 0..7 (4 sp each)
  const int f  = t & 127;
  int f4 = wlin * 128 + f;        // global float4 idx in [0, 32768)
  int b2 = f4 >> 12, rest = f4 & 4095;
  const float4* src = (const float4*)Gpart;
  float4 a = make_float4(0.f, 0.f, 0.f, 0.f);
#pragma unroll
  for (int k = 0; k < 4; ++k) {
    int sp = sq * 4 + k;
    float4 v = src[(size_t)(b2 * SP + sp) * (D * D / 4) + rest];
    a.x += v.x; a.y += v.y; a.z += v.z; a.w += v.w;
  }
  cbuf[sq][f] = a;
  __syncthreads();
  if (t < 128) {
    float4 acc = make_float4(0.f, 0.f, 0.f, 0.f);
#pragma unroll
    for (int g2 = 0; g2 < 8; ++g2) {
      float4 v = cbuf[g2][t];
      acc.x += v.x; acc.y += v.y; acc.z += v.z; acc.w += v.w;
    }
    ((float4*)G)[wlin * 128 + t] = acc;
  }
}

// ---- kernel 3: W_b rows [4s,4s+4) = scale * sum_h Q_h[rows,:] G_b V_h^T
// QG: thread=(h,row-pair,col-pair), U -> cbuf (coalesced G reads).
// WV: wave = 8 output rows i, lanes sweep c (V rows read coalesced), shfl reduce.
__global__ __launch_bounds__(1024, 1) void k_qgwv(const float* __restrict__ Ql,
                                                  const float* __restrict__ Vl,
                                                  const float* __restrict__ G,
                                                  float* __restrict__ W) {
  const int s = blockIdx.x, b = blockIdx.y;
  const int t = threadIdx.x;
  __shared__ float cbuf[32][D];     // U rows: [h*4+p][c]
  const float* Gb = G + (size_t)b * D * D;
  const int p0 = s * 4;
  // --- QG
  {
    const int h  = t >> 7;          // 0..7 (wave-uniform)
    const int pp = (t >> 6) & 1;    // 0..1 (wave-uniform)
    const int c2 = t & 63;
    const int pa = pp * 2, pb = pp * 2 + 1;
    const float* Qa = Ql + ((size_t)h * D + (p0 + pa)) * D;
    const float* Qb = Ql + ((size_t)h * D + (p0 + pb)) * D;
    float ua0 = 0.f, ua1 = 0.f, ub0 = 0.f, ub1 = 0.f;
    for (int q4 = 0; q4 < 32; ++q4) {
      float4 qa = *(const float4*)&Qa[q4 * 4];   // wave-uniform broadcast
      float4 qb = *(const float4*)&Qb[q4 * 4];
      float2 g0 = *(const float2*)&Gb[(size_t)(q4 * 4 + 0) * D + 2 * c2];
      float2 g1 = *(const float2*)&Gb[(size_t)(q4 * 4 + 1) * D + 2 * c2];
      float2 g2 = *(const float2*)&Gb[(size_t)(q4 * 4 + 2) * D + 2 * c2];
      float2 g3 = *(const float2*)&Gb[(size_t)(q4 * 4 + 3) * D + 2 * c2];
      ua0 = fmaf(qa.x, g0.x, ua0); ua1 = fmaf(qa.x, g0.y, ua1);
      ub0 = fmaf(qb.x, g0.x, ub0); ub1 = fmaf(qb.x, g0.y, ub1);
      ua0 = fmaf(qa.y, g1.x, ua0); ua1 = fmaf(qa.y, g1.y, ua1);
      ub0 = fmaf(qb.y, g1.x, ub0); ub1 = fmaf(qb.y, g1.y, ub1);
      ua0 = fmaf(qa.z, g2.x, ua0); ua1 = fmaf(qa.z, g2.y, ua1);
      ub0 = fmaf(qb.z, g2.x, ub0); ub1 = fmaf(qb.z, g2.y, ub1);
      ua0 = fmaf(qa.w, g3.x, ua0); ua1 = fmaf(qa.w, g3.y, ua1);
      ub0 = fmaf(qb.w, g3.x, ub0); ub1 = fmaf(qb.w, g3.y, ub1);
    }
    *(float2*)&cbuf[h * 4 + pa][2 * c2] = make_float2(ua0, ua1);
    *(float2*)&cbuf[h * 4 + pb][2 * c2] = make_float2(ub0, ub1);
  }
  __syncthreads();                  // all U rows visible
  // --- WV
  {
    const int w = t >> 6, lane = t & 63;   // 16 waves x 8 i-rows each
    const float scale = 1.0f / ((float)N * (float)NH);
    float* Wb = W + (size_t)b * D * D;
    for (int ii = 0; ii < 8; ++ii) {
      const int i = w * 8 + ii;
      float a0 = 0.f, a1 = 0.f, a2 = 0.f, a3 = 0.f;
#pragma unroll
      for (int h = 0; h < NH; ++h) {
        float2 v  = *(const float2*)&Vl[((size_t)h * D + i) * D + 2 * lane]; // coalesced
        float2 u0 = *(const float2*)&cbuf[h * 4 + 0][2 * lane];
        float2 u1 = *(const float2*)&cbuf[h * 4 + 1][2 * lane];
        float2 u2 = *(const float2*)&cbuf[h * 4 + 2][2 * lane];
        float2 u3 = *(const float2*)&cbuf[h * 4 + 3][2 * lane];
        a0 = fmaf(u0.x, v.x, a0); a0 = fmaf(u0.y, v.y, a0);
        a1 = fmaf(u1.x, v.x, a1); a1 = fmaf(u1.y, v.y, a1);
        a2 = fmaf(u2.x, v.x, a2); a2 = fmaf(u2.y, v.y, a2);
        a3 = fmaf(u3.x, v.x, a3); a3 = fmaf(u3.y, v.y, a3);
      }
#pragma unroll
      for (int off = 32; off >= 1; off >>= 1) {   // 64-lane reduce
        a0 += __shfl_xor(a0, off, 64);
        a1 += __shfl_xor(a1, off, 64);
        a2 += __shfl_xor(a2, off, 64);
        a3 += __shfl_xor(a3, off, 64);
      }
      if (lane == 0) {
        Wb[(size_t)(p0 + 0) * D + i] = a0 * scale;
        Wb[(size_t)(p0 + 1) * D + i] = a1 * scale;
        Wb[(size_t)(p0 + 2) * D + i] = a2 * scale;
        Wb[(size_t)(p0 + 3) * D + i] = a3 * scale;
      }
    }
  }
}

// ---- kernel 4: Zout[rows] = Zl[rows] + Zl[rows] @ W_b
__global__ __launch_bounds__(1024, 1) void k_upd(const float* __restrict__ W,
                                                 const float* __restrict__ Zl,
                                                 float* __restrict__ Zout) {
  const int s = blockIdx.x, b = blockIdx.y;
  const int t = threadIdx.x;
  __shared__ float zs[RPS][PAD];
  const float* Zb = Zl + ((size_t)b * N + (size_t)s * RPS) * D;
#pragma unroll
  for (int j = 0; j < 2; ++j) {
    int fi = t + j * 1024;
    int row = fi >> 5, c4 = fi & 31;
    *(float4*)&zs[row][c4 * 4] = ((const float4*)Zb)[fi];
  }
  __syncthreads();
  const float* Wb = W + (size_t)b * D * D;
  const int ni = t >> 5, ii = t & 31;   // 32 row-groups x 32 col-groups
  const int n0 = ni * 2;
  float acc[2][4];
#pragma unroll
  for (int i = 0; i < 2; ++i) {         // residual init: out = Z + Z@W
    float4 z0 = *(const float4*)&zs[n0 + i][ii * 4];
    acc[i][0] = z0.x; acc[i][1] = z0.y; acc[i][2] = z0.z; acc[i][3] = z0.w;
  }
#pragma unroll 2
  for (int p4 = 0; p4 < 32; ++p4) {
    float wreg[4][4];
#pragma unroll
    for (int k = 0; k < 4; ++k)         // coalesced, L1/L2-hot
      *(float4*)wreg[k] = *(const float4*)&Wb[(size_t)(p4 * 4 + k) * D + ii * 4];
#pragma unroll
    for (int i = 0; i < 2; ++i) {
      float zreg[4];
      *(float4*)zreg = *(const float4*)&zs[n0 + i][p4 * 4];
#pragma unroll
      for (int k = 0; k < 4; ++k)
#pragma unroll
        for (int c = 0; c < 4; ++c)
          acc[i][c] = fmaf(zreg[k], wreg[k][c], acc[i][c]);
    }
  }
  float* Zo = Zout + ((size_t)b * N + (size_t)s * RPS) * D;
#pragma unroll
  for (int i = 0; i < 2; ++i)
    *(float4*)&Zo[(size_t)(n0 + i) * D + ii * 4] =
        make_float4(acc[i][0], acc[i][1], acc[i][2], acc[i][3]);
}

extern "C" void kernel_launch(void* const* d_in, const int* in_sizes, int n_in,
                              void* d_out, int out_size, void* d_ws, size_t ws_size,
                              hipStream_t stream) {
  const float* Zin = (const float*)d_in[0];
  const float* Vm  = (const float*)d_in[1];   // [NL][NH][1][D][D]
  const float* Qm  = (const float*)d_in[2];   // [NL][NH][1][D][D]
  float* Zout = (float*)d_out;

  // workspace layout (17 MB, proven size):
  //   [0, 16MB)        : Gpart [B][SP][D][D]
  //   [16MB, +512KB)   : G     [B][D][D]
  //   [16.5MB, +512KB) : W     [B][D][D]
  char* ws = (char*)d_ws;
  float* Gpart = (float*)ws;
  float* G     = (float*)(ws + (size_t)B * SP * D * D * sizeof(float));
  float* W     = (float*)(ws + (size_t)B * SP * D * D * sizeof(float)
                             + (size_t)B * D * D * sizeof(float));

  const float* Zl = Zin;                      // layer input (Zin for l=0, Zout after)
  for (int l = 0; l < NL; ++l) {
    const float* Ql = Qm + (size_t)l * NH * D * D;
    const float* Vl = Vm + (size_t)l * NH * D * D;
    k_gram<<<dim3(SP, B), 1024, 0, stream>>>(Zl, Gpart);
    k_gred<<<dim3(SP, B), 1024, 0, stream>>>(Gpart, G);
    k_qgwv<<<dim3(SP, B), 1024, 0, stream>>>(Ql, Vl, G, W);
    k_upd <<<dim3(SP, B), 1024, 0, stream>>>(W, Zl, Zout);
    Zl = Zout;
  }
}

// Round 12
// 277.607 us; speedup vs baseline: 3.1425x; 1.1755x over previous
//
#include <hip/hip_runtime.h>

// Transformer_F: Z <- Z + (1/H) sum_h (Z Q_h Z^T)(Z V_h^T)/N, 4 layers.
// Reassociated: G_b = Z_b^T Z_b ; W_b = (1/(N*H)) sum_h Q_h G_b V_h^T ; Z_b += Z_b W_b.
// Round-8 lesson: per-kernel-boundary tax ~10us (launch + XCD cache acquire/release)
// dominates at this problem size -> minimize graph nodes.
// 13 nodes: k_gram0, then per layer {k_gred, k_qgwv, k_updg} with k_updg fusing
// the NEXT layer's Gram partial (computed from the fresh Z tile already in LDS).
// (3rd resubmission: rounds 9-11 never acquired a GPU; this design is unmeasured.)

constexpr int B  = 8;
constexpr int N  = 2048;
constexpr int D  = 128;
constexpr int NL = 4;
constexpr int NH = 8;
constexpr int SP = 32;          // N-splits (grid = SP x B per kernel)
constexpr int RPS = N / SP;     // 64 rows per WG
constexpr int PAD = 132;        // padded LDS row stride for zs (floats)

// ---- kernel 1 (layer 0 only): Gram partial of Zin.
__global__ __launch_bounds__(1024, 1) void k_gram0(const float* __restrict__ Zl,
                                                   float* __restrict__ Gpart) {
  const int s = blockIdx.x, b = blockIdx.y;
  const int t = threadIdx.x;
  __shared__ float zs[RPS][PAD];
  const float* Zb = Zl + ((size_t)b * N + (size_t)s * RPS) * D;
#pragma unroll
  for (int j = 0; j < 2; ++j) {
    int fi = t + j * 1024;          // float4 index into 64x128
    int row = fi >> 5, c4 = fi & 31;
    *(float4*)&zs[row][c4 * 4] = ((const float4*)Zb)[fi];
  }
  __syncthreads();
  const int ti = t >> 5, tj = t & 31;   // 32x32 grid of 4x4 tiles
  float g[4][4];
#pragma unroll
  for (int i = 0; i < 4; ++i)
#pragma unroll
    for (int j = 0; j < 4; ++j) g[i][j] = 0.0f;
#pragma unroll 4
  for (int k = 0; k < RPS; ++k) {
    float a[4], bb[4];
    *(float4*)&a[0]  = *(const float4*)&zs[k][ti * 4];
    *(float4*)&bb[0] = *(const float4*)&zs[k][tj * 4];
#pragma unroll
    for (int i = 0; i < 4; ++i)
#pragma unroll
      for (int j = 0; j < 4; ++j)
        g[i][j] = fmaf(a[i], bb[j], g[i][j]);
  }
  float* out = Gpart + ((size_t)b * SP + s) * D * D;
#pragma unroll
  for (int i = 0; i < 4; ++i)
    *(float4*)&out[(ti * 4 + i) * D + tj * 4] =
        make_float4(g[i][0], g[i][1], g[i][2], g[i][3]);
}

// ---- kernel 2: reduce Gpart -> G. Each WG owns 128 float4 of G.
__global__ __launch_bounds__(1024, 1) void k_gred(const float* __restrict__ Gpart,
                                                  float* __restrict__ G) {
  const int s = blockIdx.x, b = blockIdx.y;
  const int t = threadIdx.x;
  const int wlin = b * SP + s;
  __shared__ float4 cbuf[8][128];
  const int sq = t >> 7;          // 0..7 (4 sp each)
  const int f  = t & 127;
  int f4 = wlin * 128 + f;        // global float4 idx in [0, 32768)
  int b2 = f4 >> 12, rest = f4 & 4095;
  const float4* src = (const float4*)Gpart;
  float4 a = make_float4(0.f, 0.f, 0.f, 0.f);
#pragma unroll
  for (int k = 0; k < 4; ++k) {
    int sp = sq * 4 + k;
    float4 v = src[(size_t)(b2 * SP + sp) * (D * D / 4) + rest];
    a.x += v.x; a.y += v.y; a.z += v.z; a.w += v.w;
  }
  cbuf[sq][f] = a;
  __syncthreads();
  if (t < 128) {
    float4 acc = make_float4(0.f, 0.f, 0.f, 0.f);
#pragma unroll
    for (int g2 = 0; g2 < 8; ++g2) {
      float4 v = cbuf[g2][t];
      acc.x += v.x; acc.y += v.y; acc.z += v.z; acc.w += v.w;
    }
    ((float4*)G)[wlin * 128 + t] = acc;
  }
}

// ---- kernel 3: W_b rows [4s,4s+4) = scale * sum_h Q_h[rows,:] G_b V_h^T
// QG: G staged through LDS in 32-row chunks (each chunk loaded ONCE, consumed by
// all 8 head-groups); thread=(h,row-pair,col-pair); U -> cbuf.
// WV: wave = 8 output rows i, lanes sweep c (V rows coalesced), shfl reduce.
__global__ __launch_bounds__(1024, 1) void k_qgwv(const float* __restrict__ Ql,
                                                  const float* __restrict__ Vl,
                                                  const float* __restrict__ G,
                                                  float* __restrict__ W) {
  const int s = blockIdx.x, b = blockIdx.y;
  const int t = threadIdx.x;
  __shared__ float gs[32][D];       // current 32-row G chunk (16 KB)
  __shared__ float cbuf[32][D];     // U rows: [h*4+p][c] (16 KB)
  const float* Gb = G + (size_t)b * D * D;
  const int p0 = s * 4;
  // --- QG
  {
    const int h  = t >> 7;          // 0..7 (wave-uniform)
    const int pp = (t >> 6) & 1;    // 0..1 (wave-uniform)
    const int c2 = t & 63;
    const int pa = pp * 2, pb = pp * 2 + 1;
    const float* Qa = Ql + ((size_t)h * D + (p0 + pa)) * D;
    const float* Qb = Ql + ((size_t)h * D + (p0 + pb)) * D;
    float ua0 = 0.f, ua1 = 0.f, ub0 = 0.f, ub1 = 0.f;
    const int srow = t >> 5, sc4 = t & 31;   // staging index: 1024 float4 per chunk
    for (int qc = 0; qc < 4; ++qc) {
      __syncthreads();              // prev chunk's readers done
      *(float4*)&gs[srow][sc4 * 4] = ((const float4*)(Gb + (size_t)qc * 32 * D))[t];
      __syncthreads();              // chunk ready
      const float* Qac = Qa + qc * 32;
      const float* Qbc = Qb + qc * 32;
#pragma unroll
      for (int q4 = 0; q4 < 8; ++q4) {
        float4 qa = *(const float4*)&Qac[q4 * 4];   // wave-uniform broadcast
        float4 qb = *(const float4*)&Qbc[q4 * 4];
        float2 g0 = *(const float2*)&gs[q4 * 4 + 0][2 * c2];
        float2 g1 = *(const float2*)&gs[q4 * 4 + 1][2 * c2];
        float2 g2 = *(const float2*)&gs[q4 * 4 + 2][2 * c2];
        float2 g3 = *(const float2*)&gs[q4 * 4 + 3][2 * c2];
        ua0 = fmaf(qa.x, g0.x, ua0); ua1 = fmaf(qa.x, g0.y, ua1);
        ub0 = fmaf(qb.x, g0.x, ub0); ub1 = fmaf(qb.x, g0.y, ub1);
        ua0 = fmaf(qa.y, g1.x, ua0); ua1 = fmaf(qa.y, g1.y, ua1);
        ub0 = fmaf(qb.y, g1.x, ub0); ub1 = fmaf(qb.y, g1.y, ub1);
        ua0 = fmaf(qa.z, g2.x, ua0); ua1 = fmaf(qa.z, g2.y, ua1);
        ub0 = fmaf(qb.z, g2.x, ub0); ub1 = fmaf(qb.z, g2.y, ub1);
        ua0 = fmaf(qa.w, g3.x, ua0); ua1 = fmaf(qa.w, g3.y, ua1);
        ub0 = fmaf(qb.w, g3.x, ub0); ub1 = fmaf(qb.w, g3.y, ub1);
      }
    }
    *(float2*)&cbuf[h * 4 + pa][2 * c2] = make_float2(ua0, ua1);
    *(float2*)&cbuf[h * 4 + pb][2 * c2] = make_float2(ub0, ub1);
  }
  __syncthreads();                  // all U rows visible
  // --- WV
  {
    const int w = t >> 6, lane = t & 63;   // 16 waves x 8 i-rows each
    const float scale = 1.0f / ((float)N * (float)NH);
    float* Wb = W + (size_t)b * D * D;
    for (int ii = 0; ii < 8; ++ii) {
      const int i = w * 8 + ii;
      float a0 = 0.f, a1 = 0.f, a2 = 0.f, a3 = 0.f;
#pragma unroll
      for (int h = 0; h < NH; ++h) {
        float2 v  = *(const float2*)&Vl[((size_t)h * D + i) * D + 2 * lane]; // coalesced
        float2 u0 = *(const float2*)&cbuf[h * 4 + 0][2 * lane];
        float2 u1 = *(const float2*)&cbuf[h * 4 + 1][2 * lane];
        float2 u2 = *(const float2*)&cbuf[h * 4 + 2][2 * lane];
        float2 u3 = *(const float2*)&cbuf[h * 4 + 3][2 * lane];
        a0 = fmaf(u0.x, v.x, a0); a0 = fmaf(u0.y, v.y, a0);
        a1 = fmaf(u1.x, v.x, a1); a1 = fmaf(u1.y, v.y, a1);
        a2 = fmaf(u2.x, v.x, a2); a2 = fmaf(u2.y, v.y, a2);
        a3 = fmaf(u3.x, v.x, a3); a3 = fmaf(u3.y, v.y, a3);
      }
#pragma unroll
      for (int off = 32; off >= 1; off >>= 1) {   // 64-lane reduce
        a0 += __shfl_xor(a0, off, 64);
        a1 += __shfl_xor(a1, off, 64);
        a2 += __shfl_xor(a2, off, 64);
        a3 += __shfl_xor(a3, off, 64);
      }
      if (lane == 0) {
        Wb[(size_t)(p0 + 0) * D + i] = a0 * scale;
        Wb[(size_t)(p0 + 1) * D + i] = a1 * scale;
        Wb[(size_t)(p0 + 2) * D + i] = a2 * scale;
        Wb[(size_t)(p0 + 3) * D + i] = a3 * scale;
      }
    }
  }
}

// ---- kernel 4: Zout[rows] = Zl[rows] + Zl[rows] @ W_b ; optionally the NEXT
//      layer's Gram partial from the fresh rows (still in LDS). In-place safe
//      (each WG touches only its own 64 rows).
__global__ __launch_bounds__(1024, 1) void k_updg(const float* __restrict__ W,
                                                  const float* __restrict__ Zl,
                                                  float* __restrict__ Zout,
                                                  float* __restrict__ Gpart,
                                                  int compute_g) {
  const int s = blockIdx.x, b = blockIdx.y;
  const int t = threadIdx.x;
  __shared__ float zs[RPS][PAD];
  const float* Zb = Zl + ((size_t)b * N + (size_t)s * RPS) * D;
#pragma unroll
  for (int j = 0; j < 2; ++j) {
    int fi = t + j * 1024;
    int row = fi >> 5, c4 = fi & 31;
    *(float4*)&zs[row][c4 * 4] = ((const float4*)Zb)[fi];
  }
  __syncthreads();
  const float* Wb = W + (size_t)b * D * D;
  const int ni = t >> 5, ii = t & 31;   // 32 row-groups x 32 col-groups
  const int n0 = ni * 2;
  float acc[2][4];
#pragma unroll
  for (int i = 0; i < 2; ++i) {         // residual init: out = Z + Z@W
    float4 z0 = *(const float4*)&zs[n0 + i][ii * 4];
    acc[i][0] = z0.x; acc[i][1] = z0.y; acc[i][2] = z0.z; acc[i][3] = z0.w;
  }
#pragma unroll 2
  for (int p4 = 0; p4 < 32; ++p4) {
    float wreg[4][4];
#pragma unroll
    for (int k = 0; k < 4; ++k)         // coalesced, L1/L2-hot
      *(float4*)wreg[k] = *(const float4*)&Wb[(size_t)(p4 * 4 + k) * D + ii * 4];
#pragma unroll
    for (int i = 0; i < 2; ++i) {
      float zreg[4];
      *(float4*)zreg = *(const float4*)&zs[n0 + i][p4 * 4];
#pragma unroll
      for (int k = 0; k < 4; ++k)
#pragma unroll
        for (int c = 0; c < 4; ++c)
          acc[i][c] = fmaf(zreg[k], wreg[k][c], acc[i][c]);
    }
  }
  __syncthreads();                       // all reads of old zs complete
  float* Zo = Zout + ((size_t)b * N + (size_t)s * RPS) * D;
#pragma unroll
  for (int i = 0; i < 2; ++i) {
    float4 v = make_float4(acc[i][0], acc[i][1], acc[i][2], acc[i][3]);
    *(float4*)&zs[n0 + i][ii * 4] = v;   // refresh LDS with new Z
    *(float4*)&Zo[(size_t)(n0 + i) * D + ii * 4] = v;
  }
  if (!compute_g) return;
  __syncthreads();                       // new zs visible to all
  // ---- fused Gram partial of the UPDATED rows (feeds next layer's k_gred)
  const int ti = t >> 5, tj = t & 31;
  float g[4][4];
#pragma unroll
  for (int i = 0; i < 4; ++i)
#pragma unroll
    for (int j = 0; j < 4; ++j) g[i][j] = 0.0f;
#pragma unroll 4
  for (int k = 0; k < RPS; ++k) {
    float a[4], bb[4];
    *(float4*)&a[0]  = *(const float4*)&zs[k][ti * 4];
    *(float4*)&bb[0] = *(const float4*)&zs[k][tj * 4];
#pragma unroll
    for (int i = 0; i < 4; ++i)
#pragma unroll
      for (int j = 0; j < 4; ++j)
        g[i][j] = fmaf(a[i], bb[j], g[i][j]);
  }
  float* out = Gpart + ((size_t)b * SP + s) * D * D;
#pragma unroll
  for (int i = 0; i < 4; ++i)
    *(float4*)&out[(ti * 4 + i) * D + tj * 4] =
        make_float4(g[i][0], g[i][1], g[i][2], g[i][3]);
}

extern "C" void kernel_launch(void* const* d_in, const int* in_sizes, int n_in,
                              void* d_out, int out_size, void* d_ws, size_t ws_size,
                              hipStream_t stream) {
  const float* Zin = (const float*)d_in[0];
  const float* Vm  = (const float*)d_in[1];   // [NL][NH][1][D][D]
  const float* Qm  = (const float*)d_in[2];   // [NL][NH][1][D][D]
  float* Zout = (float*)d_out;

  // workspace layout (17 MB):
  //   [0, 16MB)        : Gpart [B][SP][D][D]
  //   [16MB, +512KB)   : G     [B][D][D]
  //   [16.5MB, +512KB) : W     [B][D][D]
  char* ws = (char*)d_ws;
  float* Gpart = (float*)ws;
  float* G     = (float*)(ws + (size_t)B * SP * D * D * sizeof(float));
  float* W     = (float*)(ws + (size_t)B * SP * D * D * sizeof(float)
                             + (size_t)B * D * D * sizeof(float));

  k_gram0<<<dim3(SP, B), 1024, 0, stream>>>(Zin, Gpart);

  const float* Zl = Zin;                      // layer input (Zin for l=0, Zout after)
  for (int l = 0; l < NL; ++l) {
    const float* Ql = Qm + (size_t)l * NH * D * D;
    const float* Vl = Vm + (size_t)l * NH * D * D;
    k_gred<<<dim3(SP, B), 1024, 0, stream>>>(Gpart, G);
    k_qgwv<<<dim3(SP, B), 1024, 0, stream>>>(Ql, Vl, G, W);
    k_updg<<<dim3(SP, B), 1024, 0, stream>>>(W, Zl, Zout, Gpart, (l < NL - 1) ? 1 : 0);
    Zl = Zout;
  }
}